// Round 5
// baseline (338.358 us; speedup 1.0000x reference)
//
#include <hip/hip_runtime.h>
#include <hip/hip_bf16.h>

#define B_N 8192
#define M_N 3129
#define M_PAD 3200
#define D_N 512

// ce streaming constants: 8192*3129 floats = 6,408,192 float4 chunks
// = 100,128 wave-windows (64 chunks each) per array; two arrays.
#define CE_WPA 100128
#define CE_WTOT (2 * CE_WPA)     // 200256 = 24 * 8344
#define CE_WAVES 8344
#define CE_BLOCKS 2086           // 8344 waves / 4 per block

#define GLOBAL_AS __attribute__((address_space(1)))
#define LDS_AS __attribute__((address_space(3)))

typedef __bf16 bf16x8 __attribute__((ext_vector_type(8)));
typedef float f32x4 __attribute__((ext_vector_type(4)));

// ---------------------------------------------------------------------------
// Fused prep: normalize mm_proj -> g, normalize ans_emb -> a (zero-padded to
// M_PAD), obj cosine rows. One wave per row; one dispatch.
#define PREP_G_BLOCKS   (B_N / 4)      // 2048
#define PREP_A_BLOCKS   (M_PAD / 4)    // 800
#define PREP_OBJ_BLOCKS (B_N / 4)      // 2048

__device__ __forceinline__ void normalize_row(
    const float* __restrict__ x, __bf16* __restrict__ y,
    int row, int nrows_src, int lane) {
  bf16x8 out;
  if (row >= nrows_src) {
    for (int j = 0; j < 8; ++j) out[j] = (__bf16)0.0f;
    *(bf16x8*)(y + (size_t)row * D_N + lane * 8) = out;
    return;
  }
  const float4* xr = (const float4*)(x + (size_t)row * D_N);
  float4 v0 = xr[lane * 2], v1 = xr[lane * 2 + 1];
  float s = v0.x*v0.x + v0.y*v0.y + v0.z*v0.z + v0.w*v0.w
          + v1.x*v1.x + v1.y*v1.y + v1.z*v1.z + v1.w*v1.w;
  for (int o = 1; o < 64; o <<= 1) s += __shfl_xor(s, o);
  float rn = 1.0f / fmaxf(sqrtf(s), 1e-8f);
  float vals[8] = {v0.x, v0.y, v0.z, v0.w, v1.x, v1.y, v1.z, v1.w};
  for (int j = 0; j < 8; ++j) out[j] = (__bf16)(vals[j] * rn);
  *(bf16x8*)(y + (size_t)row * D_N + lane * 8) = out;
}

__global__ __launch_bounds__(256) void prep_kernel(
    const float* __restrict__ mm_proj, const float* __restrict__ ans_emb,
    const float* __restrict__ v_max, const float* __restrict__ mm,
    __bf16* __restrict__ g, __bf16* __restrict__ a,
    float* __restrict__ obj) {
  int blk = blockIdx.x;
  int wid = threadIdx.x >> 6, lane = threadIdx.x & 63;
  if (blk < PREP_G_BLOCKS) {
    normalize_row(mm_proj, g, blk * 4 + wid, B_N, lane);
  } else if (blk < PREP_G_BLOCKS + PREP_A_BLOCKS) {
    normalize_row(ans_emb, a, (blk - PREP_G_BLOCKS) * 4 + wid, M_N, lane);
  } else {
    int b = (blk - PREP_G_BLOCKS - PREP_A_BLOCKS) * 4 + wid;
    const float4* vr = (const float4*)(v_max + (size_t)b * D_N);
    const float4* mr = (const float4*)(mm + (size_t)b * D_N);
    float4 a0 = vr[lane * 2], a1 = vr[lane * 2 + 1];
    float4 b0 = mr[lane * 2], b1 = mr[lane * 2 + 1];
    float sv = a0.x*a0.x + a0.y*a0.y + a0.z*a0.z + a0.w*a0.w
             + a1.x*a1.x + a1.y*a1.y + a1.z*a1.z + a1.w*a1.w;
    float sm = b0.x*b0.x + b0.y*b0.y + b0.z*b0.z + b0.w*b0.w
             + b1.x*b1.x + b1.y*b1.y + b1.z*b1.z + b1.w*b1.w;
    float sd = a0.x*b0.x + a0.y*b0.y + a0.z*b0.z + a0.w*b0.w
             + a1.x*b1.x + a1.y*b1.y + a1.z*b1.z + a1.w*b1.w;
    for (int o = 1; o < 64; o <<= 1) {
      sv += __shfl_xor(sv, o);
      sm += __shfl_xor(sm, o);
      sd += __shfl_xor(sd, o);
    }
    if (lane == 0) {
      float dist = sd / (fmaxf(sqrtf(sv), 1e-8f) * fmaxf(sqrtf(sm), 1e-8f));
      obj[b] = 1.0f - dist;
    }
  }
}

// ---------------------------------------------------------------------------
// pos[b] = dot(g[b], a[cid[b]]) — one wave per row. Matches the MFMA d_logit
// element to fp32 rounding (same bf16 inputs, fp32 accumulation).
__global__ __launch_bounds__(256) void pos_kernel(
    const __bf16* __restrict__ g, const __bf16* __restrict__ a,
    const int* __restrict__ cid, float* __restrict__ pos) {
  int wid = threadIdx.x >> 6, lane = threadIdx.x & 63;
  int b = blockIdx.x * 4 + wid;
  if (b >= B_N) return;
  int label = cid[b];
  bf16x8 gv = *(const bf16x8*)(g + (size_t)b * D_N + lane * 8);
  bf16x8 av = *(const bf16x8*)(a + (size_t)label * D_N + lane * 8);
  float s = 0.0f;
  for (int j = 0; j < 8; ++j) s += (float)gv[j] * (float)av[j];
  for (int o = 1; o < 64; o <<= 1) s += __shfl_xor(s, o);
  if (lane == 0) pos[b] = s;
}

// ---------------------------------------------------------------------------
// Fused cosine-GEMM + exp row-sum: den[b] += sum_m exp(dot(g[b], a[m])).
// 128x128 tile, K-step 32, global_load_lds width-16 staging (L2-warm inputs
// -> short latency, DMA queue is fine here), mfma_f32_16x16x32_bf16.
__global__ __launch_bounds__(256) void nce_gemm_kernel(
    const __bf16* __restrict__ g, const __bf16* __restrict__ a,
    float* __restrict__ den) {
  __shared__ __bf16 As[128 * 32];
  __shared__ __bf16 Bs[128 * 32];
  const int t = threadIdx.x;
  const int brow0 = blockIdx.y * 128;
  const int mrow0 = blockIdx.x * 128;
  const int lane = t & 63;
  const int wid = t >> 6;
  const int wrow = wid >> 1;      // 0..1
  const int wcol = wid & 1;       // 0..1
  const int r = lane & 15;
  const int quad = lane >> 4;

  f32x4 acc[4][4];
  for (int i = 0; i < 4; ++i)
    for (int j = 0; j < 4; ++j)
      acc[i][j] = f32x4{0.f, 0.f, 0.f, 0.f};

  for (int k0 = 0; k0 < D_N; k0 += 32) {
    __syncthreads();
    for (int i = 0; i < 2; ++i) {
      int s = t + i * 256;
      int row = s >> 2;
      int kq = (s & 3) << 3;
      const __bf16* ga = g + (size_t)(brow0 + row) * D_N + (k0 + kq);
      __builtin_amdgcn_global_load_lds((const GLOBAL_AS void*)ga,
                                       (LDS_AS void*)(As + s * 8), 16, 0, 0);
      const __bf16* gb = a + (size_t)(mrow0 + row) * D_N + (k0 + kq);
      __builtin_amdgcn_global_load_lds((const GLOBAL_AS void*)gb,
                                       (LDS_AS void*)(Bs + s * 8), 16, 0, 0);
    }
    __syncthreads();
    bf16x8 af[4], bf[4];
    for (int i = 0; i < 4; ++i)
      af[i] = *(const bf16x8*)(As + (wrow * 64 + i * 16 + r) * 32 + quad * 8);
    for (int j = 0; j < 4; ++j)
      bf[j] = *(const bf16x8*)(Bs + (wcol * 64 + j * 16 + r) * 32 + quad * 8);
    for (int i = 0; i < 4; ++i)
      for (int j = 0; j < 4; ++j)
        acc[i][j] = __builtin_amdgcn_mfma_f32_16x16x32_bf16(af[i], bf[j],
                                                            acc[i][j], 0, 0, 0);
  }

  // C/D layout: col = lane&15, row = quad*4 + reg.
  for (int i = 0; i < 4; ++i) {
    for (int reg = 0; reg < 4; ++reg) {
      float s = 0.0f;
      for (int j = 0; j < 4; ++j) {
        int m = mrow0 + wcol * 64 + j * 16 + r;
        if (m < M_N) s += __expf(acc[i][j][reg]);
      }
      s += __shfl_xor(s, 1);
      s += __shfl_xor(s, 2);
      s += __shfl_xor(s, 4);
      s += __shfl_xor(s, 8);
      if (r == 0) {
        int b = brow0 + wrow * 64 + i * 16 + quad * 4 + reg;
        atomicAdd(den + b, s);
      }
    }
  }
}

// ---------------------------------------------------------------------------
// CE exp-sums as pure m13-style streaming: no LDS, low VGPR, 32 waves/CU,
// 4 independent float4 loads per group. Rounds 2-4 all plateaued at ~10.5
// GB/s/CU regardless of load structure (block-per-row + shallow MLP); this
// clones the measured-6.3TB/s copy profile instead.
// Each wave-window = 64 consecutive float4 = 1024 floats, spans <= 2 rows
// (1024 < 3129): two masked lane-sums, 12 shfls, <= 2 spread atomics.
// rowsum layout: [0..8191] = logits_q rows, [8192..16383] = logits_rubi.
__global__ __launch_bounds__(256) void ce_sum_kernel(
    const float* __restrict__ lq, const float* __restrict__ lr,
    float* __restrict__ rowsum) {
  const int lane = threadIdx.x & 63;
  const int gw = (int)((blockIdx.x * 256 + threadIdx.x) >> 6);  // 0..8343
#pragma unroll 1
  for (int gidx = 0; gidx < 6; ++gidx) {
    float4 v[4];
    unsigned e0[4];
    int arr[4];
#pragma unroll
    for (int k = 0; k < 4; ++k) {
      int w = gw + (gidx * 4 + k) * CE_WAVES;   // wave-uniform, < CE_WTOT
      int aidx = (w >= CE_WPA) ? 1 : 0;
      unsigned chunk = (unsigned)(w - aidx * CE_WPA) * 64u + (unsigned)lane;
      e0[k] = chunk * 4u;
      arr[k] = aidx;
      const float* base = aidx ? lr : lq;
      v[k] = *(const float4*)(base + (size_t)chunk * 4u);
    }
#pragma unroll
    for (int k = 0; k < 4; ++k) {
      unsigned row0 = e0[k] / M_N;            // magic-mul div
      unsigned bound = (row0 + 1u) * M_N;
      float ex0 = __expf(v[k].x), ex1 = __expf(v[k].y),
            ex2 = __expf(v[k].z), ex3 = __expf(v[k].w);
      float s_lo = 0.f, s_hi = 0.f;
      if (e0[k] + 0u < bound) s_lo += ex0; else s_hi += ex0;
      if (e0[k] + 1u < bound) s_lo += ex1; else s_hi += ex1;
      if (e0[k] + 2u < bound) s_lo += ex2; else s_hi += ex2;
      if (e0[k] + 3u < bound) s_lo += ex3; else s_hi += ex3;
      unsigned rA = (unsigned)__builtin_amdgcn_readfirstlane((int)row0);
      float cA = (row0 == rA) ? s_lo : 0.f;
      float cB = (row0 == rA) ? s_hi : s_lo;
      for (int o = 1; o < 64; o <<= 1) {
        cA += __shfl_xor(cA, o);
        cB += __shfl_xor(cB, o);
      }
      if (lane == 0) {
        float* rs = rowsum + (arr[k] ? B_N : 0);
        atomicAdd(rs + rA, cA);
        if (cB != 0.f) atomicAdd(rs + rA + 1, cB);
      }
    }
  }
}

// ---------------------------------------------------------------------------
// Final reduce: per-row losses -> acc[0..3] (32 adders/address). Folds the
// CE finish (log(rowsum) - label gather) in. acc must be pre-zeroed.
__global__ __launch_bounds__(256) void final_reduce_kernel(
    const float* __restrict__ den, const float* __restrict__ pos,
    const float* __restrict__ rowsum,
    const float* __restrict__ lq, const float* __restrict__ lr,
    const int* __restrict__ cid, const float* __restrict__ obj,
    float* __restrict__ acc) {
  int b = blockIdx.x * 256 + threadIdx.x;  // 32*256 == B_N exactly
  int lab = cid[b];
  float xq = lq[(size_t)b * M_N + lab];
  float xr = lr[(size_t)b * M_N + lab];
  float s_nce = logf(den[b]) - pos[b];
  float s_ceq = logf(rowsum[b]) - xq;
  float s_cer = logf(rowsum[B_N + b]) - xr;
  float s_obj = obj[b];
  for (int o = 1; o < 64; o <<= 1) {
    s_nce += __shfl_xor(s_nce, o);
    s_ceq += __shfl_xor(s_ceq, o);
    s_cer += __shfl_xor(s_cer, o);
    s_obj += __shfl_xor(s_obj, o);
  }
  __shared__ float red[4][4];
  int wid = threadIdx.x >> 6;
  if ((threadIdx.x & 63) == 0) {
    red[wid][0] = s_nce; red[wid][1] = s_ceq;
    red[wid][2] = s_cer; red[wid][3] = s_obj;
  }
  __syncthreads();
  if (threadIdx.x < 4) {
    float v = red[0][threadIdx.x] + red[1][threadIdx.x]
            + red[2][threadIdx.x] + red[3][threadIdx.x];
    atomicAdd(acc + threadIdx.x, v);
  }
}

// Stage 2: combine.
__global__ void final_combine_kernel(const float* __restrict__ acc,
                                     float* __restrict__ out) {
  if (threadIdx.x == 0) {
    float nce = acc[0] / (float)B_N;
    float ceq = acc[1] / (float)B_N;
    float cer = acc[2] / (float)B_N;
    float ob  = acc[3] / (float)B_N;
    float fusion = (cer + ob + nce) * (1.0f / 3.0f);
    out[0] = fusion + ceq;  // question_loss_weight = 1.0
    out[1] = fusion;
    out[2] = ceq;
  }
}

// ---------------------------------------------------------------------------
extern "C" void kernel_launch(void* const* d_in, const int* in_sizes, int n_in,
                              void* d_out, int out_size, void* d_ws, size_t ws_size,
                              hipStream_t stream) {
  const float* mm_proj     = (const float*)d_in[0];
  const float* ans_emb     = (const float*)d_in[1];
  const float* v_max       = (const float*)d_in[2];
  const float* mm          = (const float*)d_in[3];
  const float* logits_q    = (const float*)d_in[4];
  const float* logits_rubi = (const float*)d_in[5];
  const int*   cid         = (const int*)d_in[6];
  float* out = (float*)d_out;

  // Workspace layout (16B-aligned):
  //   g_bf16 : 8192*512*2 = 8,388,608 B
  //   a_bf16 : 3200*512*2 = 3,276,800 B
  //   zero region: den[8192] | rowsum[16384] | acc[4]   (one memset)
  //   pos[8192], obj[8192]
  char* ws = (char*)d_ws;
  __bf16* g = (__bf16*)ws;
  __bf16* a = (__bf16*)(ws + 8388608);
  float* den    = (float*)(ws + 8388608 + 3276800);
  float* rowsum = den + B_N;
  float* acc    = rowsum + 2 * B_N;
  float* pos    = acc + 4;
  float* obj    = pos + B_N;

  hipMemsetAsync(den, 0, (size_t)(3 * B_N + 4) * sizeof(float), stream);

  prep_kernel<<<PREP_G_BLOCKS + PREP_A_BLOCKS + PREP_OBJ_BLOCKS, 256, 0,
                stream>>>(mm_proj, ans_emb, v_max, mm, g, a, obj);
  pos_kernel<<<B_N / 4, 256, 0, stream>>>(g, a, cid, pos);
  nce_gemm_kernel<<<dim3(M_PAD / 128, B_N / 128), 256, 0, stream>>>(g, a, den);
  ce_sum_kernel<<<CE_BLOCKS, 256, 0, stream>>>(logits_q, logits_rubi, rowsum);
  final_reduce_kernel<<<B_N / 256, 256, 0, stream>>>(den, pos, rowsum,
                                                     logits_q, logits_rubi,
                                                     cid, obj, acc);
  final_combine_kernel<<<1, 64, 0, stream>>>(acc, out);
}

// Round 6
// 329.722 us; speedup vs baseline: 1.0262x; 1.0262x over previous
//
#include <hip/hip_runtime.h>
#include <hip/hip_bf16.h>

#define B_N 8192
#define M_N 3129
#define M_PAD 3200
#define D_N 512

// ce streaming: each wave owns a contiguous span of 3072 floats (12 float4
// wave-loads). 3072 < 3129 => at most ONE row boundary per span => 2 buckets.
// 8192*3129 floats = 6,408,192 float4 = 100,128 wave-loads = 8344 spans/array.
#define CE_L 12
#define CE_SPAN (CE_L * 256)     // 3072 floats
#define CE_WPA 8344              // spans per array
#define CE_WTOT (2 * CE_WPA)     // 16688
#define CE_BLOCKS (CE_WTOT / 4)  // 4172

#define GLOBAL_AS __attribute__((address_space(1)))
#define LDS_AS __attribute__((address_space(3)))

typedef __bf16 bf16x8 __attribute__((ext_vector_type(8)));
typedef float f32x4 __attribute__((ext_vector_type(4)));

// ---------------------------------------------------------------------------
// Fused prep: normalize mm_proj -> g, normalize ans_emb -> a (zero-padded to
// M_PAD), obj cosine rows. One wave per row; one dispatch.
#define PREP_G_BLOCKS   (B_N / 4)      // 2048
#define PREP_A_BLOCKS   (M_PAD / 4)    // 800
#define PREP_OBJ_BLOCKS (B_N / 4)      // 2048

__device__ __forceinline__ void normalize_row(
    const float* __restrict__ x, __bf16* __restrict__ y,
    int row, int nrows_src, int lane) {
  bf16x8 out;
  if (row >= nrows_src) {
    for (int j = 0; j < 8; ++j) out[j] = (__bf16)0.0f;
    *(bf16x8*)(y + (size_t)row * D_N + lane * 8) = out;
    return;
  }
  const float4* xr = (const float4*)(x + (size_t)row * D_N);
  float4 v0 = xr[lane * 2], v1 = xr[lane * 2 + 1];
  float s = v0.x*v0.x + v0.y*v0.y + v0.z*v0.z + v0.w*v0.w
          + v1.x*v1.x + v1.y*v1.y + v1.z*v1.z + v1.w*v1.w;
  for (int o = 1; o < 64; o <<= 1) s += __shfl_xor(s, o);
  float rn = 1.0f / fmaxf(sqrtf(s), 1e-8f);
  float vals[8] = {v0.x, v0.y, v0.z, v0.w, v1.x, v1.y, v1.z, v1.w};
  for (int j = 0; j < 8; ++j) out[j] = (__bf16)(vals[j] * rn);
  *(bf16x8*)(y + (size_t)row * D_N + lane * 8) = out;
}

__global__ __launch_bounds__(256) void prep_kernel(
    const float* __restrict__ mm_proj, const float* __restrict__ ans_emb,
    const float* __restrict__ v_max, const float* __restrict__ mm,
    __bf16* __restrict__ g, __bf16* __restrict__ a,
    float* __restrict__ obj) {
  int blk = blockIdx.x;
  int wid = threadIdx.x >> 6, lane = threadIdx.x & 63;
  if (blk < PREP_G_BLOCKS) {
    normalize_row(mm_proj, g, blk * 4 + wid, B_N, lane);
  } else if (blk < PREP_G_BLOCKS + PREP_A_BLOCKS) {
    normalize_row(ans_emb, a, (blk - PREP_G_BLOCKS) * 4 + wid, M_N, lane);
  } else {
    int b = (blk - PREP_G_BLOCKS - PREP_A_BLOCKS) * 4 + wid;
    const float4* vr = (const float4*)(v_max + (size_t)b * D_N);
    const float4* mr = (const float4*)(mm + (size_t)b * D_N);
    float4 a0 = vr[lane * 2], a1 = vr[lane * 2 + 1];
    float4 b0 = mr[lane * 2], b1 = mr[lane * 2 + 1];
    float sv = a0.x*a0.x + a0.y*a0.y + a0.z*a0.z + a0.w*a0.w
             + a1.x*a1.x + a1.y*a1.y + a1.z*a1.z + a1.w*a1.w;
    float sm = b0.x*b0.x + b0.y*b0.y + b0.z*b0.z + b0.w*b0.w
             + b1.x*b1.x + b1.y*b1.y + b1.z*b1.z + b1.w*b1.w;
    float sd = a0.x*b0.x + a0.y*b0.y + a0.z*b0.z + a0.w*b0.w
             + a1.x*b1.x + a1.y*b1.y + a1.z*b1.z + a1.w*b1.w;
    for (int o = 1; o < 64; o <<= 1) {
      sv += __shfl_xor(sv, o);
      sm += __shfl_xor(sm, o);
      sd += __shfl_xor(sd, o);
    }
    if (lane == 0) {
      float dist = sd / (fmaxf(sqrtf(sv), 1e-8f) * fmaxf(sqrtf(sm), 1e-8f));
      obj[b] = 1.0f - dist;
    }
  }
}

// ---------------------------------------------------------------------------
// pos[b] = dot(g[b], a[cid[b]]) — one wave per row. Matches the MFMA d_logit
// element to fp32 rounding (same bf16 inputs, fp32 accumulation).
__global__ __launch_bounds__(256) void pos_kernel(
    const __bf16* __restrict__ g, const __bf16* __restrict__ a,
    const int* __restrict__ cid, float* __restrict__ pos) {
  int wid = threadIdx.x >> 6, lane = threadIdx.x & 63;
  int b = blockIdx.x * 4 + wid;
  if (b >= B_N) return;
  int label = cid[b];
  bf16x8 gv = *(const bf16x8*)(g + (size_t)b * D_N + lane * 8);
  bf16x8 av = *(const bf16x8*)(a + (size_t)label * D_N + lane * 8);
  float s = 0.0f;
  for (int j = 0; j < 8; ++j) s += (float)gv[j] * (float)av[j];
  for (int o = 1; o < 64; o <<= 1) s += __shfl_xor(s, o);
  if (lane == 0) pos[b] = s;
}

// ---------------------------------------------------------------------------
// Fused cosine-GEMM + exp row-sum: den[b] += sum_m exp(dot(g[b], a[m])).
// 128x128 tile, K-step 32, global_load_lds width-16 staging,
// mfma_f32_16x16x32_bf16, 2x2 waves each computing 64x64 (4x4 MFMA tiles).
__global__ __launch_bounds__(256) void nce_gemm_kernel(
    const __bf16* __restrict__ g, const __bf16* __restrict__ a,
    float* __restrict__ den) {
  __shared__ __bf16 As[128 * 32];
  __shared__ __bf16 Bs[128 * 32];
  const int t = threadIdx.x;
  const int brow0 = blockIdx.y * 128;
  const int mrow0 = blockIdx.x * 128;
  const int lane = t & 63;
  const int wid = t >> 6;
  const int wrow = wid >> 1;      // 0..1
  const int wcol = wid & 1;       // 0..1
  const int r = lane & 15;
  const int quad = lane >> 4;

  f32x4 acc[4][4];
  for (int i = 0; i < 4; ++i)
    for (int j = 0; j < 4; ++j)
      acc[i][j] = f32x4{0.f, 0.f, 0.f, 0.f};

  for (int k0 = 0; k0 < D_N; k0 += 32) {
    __syncthreads();
    for (int i = 0; i < 2; ++i) {
      int s = t + i * 256;
      int row = s >> 2;
      int kq = (s & 3) << 3;
      const __bf16* ga = g + (size_t)(brow0 + row) * D_N + (k0 + kq);
      __builtin_amdgcn_global_load_lds((const GLOBAL_AS void*)ga,
                                       (LDS_AS void*)(As + s * 8), 16, 0, 0);
      const __bf16* gb = a + (size_t)(mrow0 + row) * D_N + (k0 + kq);
      __builtin_amdgcn_global_load_lds((const GLOBAL_AS void*)gb,
                                       (LDS_AS void*)(Bs + s * 8), 16, 0, 0);
    }
    __syncthreads();
    bf16x8 af[4], bf[4];
    for (int i = 0; i < 4; ++i)
      af[i] = *(const bf16x8*)(As + (wrow * 64 + i * 16 + r) * 32 + quad * 8);
    for (int j = 0; j < 4; ++j)
      bf[j] = *(const bf16x8*)(Bs + (wcol * 64 + j * 16 + r) * 32 + quad * 8);
    for (int i = 0; i < 4; ++i)
      for (int j = 0; j < 4; ++j)
        acc[i][j] = __builtin_amdgcn_mfma_f32_16x16x32_bf16(af[i], bf[j],
                                                            acc[i][j], 0, 0, 0);
  }

  // C/D layout: col = lane&15, row = quad*4 + reg.
  for (int i = 0; i < 4; ++i) {
    for (int reg = 0; reg < 4; ++reg) {
      float s = 0.0f;
      for (int j = 0; j < 4; ++j) {
        int m = mrow0 + wcol * 64 + j * 16 + r;
        if (m < M_N) s += __expf(acc[i][j][reg]);
      }
      s += __shfl_xor(s, 1);
      s += __shfl_xor(s, 2);
      s += __shfl_xor(s, 4);
      s += __shfl_xor(s, 8);
      if (r == 0) {
        int b = brow0 + wrow * 64 + i * 16 + quad * 4 + reg;
        atomicAdd(den + b, s);
      }
    }
  }
}

// ---------------------------------------------------------------------------
// CE exp-sums, span-per-wave streaming. Round-5 lesson: per-window shfl
// reductions (288 DS ops/wave, dependent chains between load groups) choke
// the DS pipe and collapse the memory duty cycle. Here each wave owns a
// CONTIGUOUS 3072-float span (< one row length => at most 1 row boundary),
// accumulates 2 buckets split by a wave-uniform bound, and does ONE 2x6-step
// shfl reduction at the end (12 DS ops/wave, 24x fewer, off the load path).
// Loads: depth-6 register pipeline, straight-line consumption.
// rowsum layout: [0..8191] = logits_q rows, [8192..16383] = logits_rubi.
__global__ __launch_bounds__(256) void ce_sum_kernel(
    const float* __restrict__ lq, const float* __restrict__ lr,
    float* __restrict__ rowsum) {
  const int lane = threadIdx.x & 63;
  const int gw = (int)((blockIdx.x * 256 + threadIdx.x) >> 6);  // 0..16687
  const int aidx = (gw >= CE_WPA) ? 1 : 0;
  const unsigned wl = (unsigned)(gw - aidx * CE_WPA);
  const unsigned f0 = wl * (unsigned)CE_SPAN;          // span start (flat)
  const unsigned r0 = f0 / (unsigned)M_N;              // magic-mul div
  const unsigned b1 = (r0 + 1u) * (unsigned)M_N;       // wave-uniform bound
  const float* base = aidx ? lr : lq;
  const float* p = base + f0 + (unsigned)lane * 4u;

  float4 buf[6];
#pragma unroll
  for (int i = 0; i < 6; ++i) buf[i] = *(const float4*)(p + i * 256);

  float a0 = 0.f, a1 = 0.f;
  const unsigned fbase = f0 + (unsigned)lane * 4u;
#pragma unroll
  for (int i = 0; i < CE_L; ++i) {
    float4 v = buf[i % 6];
    if (i + 6 < CE_L) buf[i % 6] = *(const float4*)(p + (i + 6) * 256);
    unsigned f = fbase + (unsigned)i * 256u;
    float e0 = __expf(v.x), e1 = __expf(v.y), e2 = __expf(v.z), e3 = __expf(v.w);
    float lo = 0.f, hi = 0.f;
    if (f + 0u < b1) lo += e0; else hi += e0;
    if (f + 1u < b1) lo += e1; else hi += e1;
    if (f + 2u < b1) lo += e2; else hi += e2;
    if (f + 3u < b1) lo += e3; else hi += e3;
    a0 += lo; a1 += hi;
  }
  for (int o = 1; o < 64; o <<= 1) {
    a0 += __shfl_xor(a0, o);
    a1 += __shfl_xor(a1, o);
  }
  if (lane == 0) {
    float* rs = rowsum + (aidx ? B_N : 0);
    atomicAdd(rs + r0, a0);
    if (a1 != 0.f) atomicAdd(rs + r0 + 1, a1);  // exact 0 iff no boundary
  }
}

// ---------------------------------------------------------------------------
// Final reduce: per-row losses -> acc[0..3] (32 adders/address). Folds the
// CE finish (log(rowsum) - label gather) in. acc must be pre-zeroed.
__global__ __launch_bounds__(256) void final_reduce_kernel(
    const float* __restrict__ den, const float* __restrict__ pos,
    const float* __restrict__ rowsum,
    const float* __restrict__ lq, const float* __restrict__ lr,
    const int* __restrict__ cid, const float* __restrict__ obj,
    float* __restrict__ acc) {
  int b = blockIdx.x * 256 + threadIdx.x;  // 32*256 == B_N exactly
  int lab = cid[b];
  float xq = lq[(size_t)b * M_N + lab];
  float xr = lr[(size_t)b * M_N + lab];
  float s_nce = logf(den[b]) - pos[b];
  float s_ceq = logf(rowsum[b]) - xq;
  float s_cer = logf(rowsum[B_N + b]) - xr;
  float s_obj = obj[b];
  for (int o = 1; o < 64; o <<= 1) {
    s_nce += __shfl_xor(s_nce, o);
    s_ceq += __shfl_xor(s_ceq, o);
    s_cer += __shfl_xor(s_cer, o);
    s_obj += __shfl_xor(s_obj, o);
  }
  __shared__ float red[4][4];
  int wid = threadIdx.x >> 6;
  if ((threadIdx.x & 63) == 0) {
    red[wid][0] = s_nce; red[wid][1] = s_ceq;
    red[wid][2] = s_cer; red[wid][3] = s_obj;
  }
  __syncthreads();
  if (threadIdx.x < 4) {
    float v = red[0][threadIdx.x] + red[1][threadIdx.x]
            + red[2][threadIdx.x] + red[3][threadIdx.x];
    atomicAdd(acc + threadIdx.x, v);
  }
}

// Stage 2: combine.
__global__ void final_combine_kernel(const float* __restrict__ acc,
                                     float* __restrict__ out) {
  if (threadIdx.x == 0) {
    float nce = acc[0] / (float)B_N;
    float ceq = acc[1] / (float)B_N;
    float cer = acc[2] / (float)B_N;
    float ob  = acc[3] / (float)B_N;
    float fusion = (cer + ob + nce) * (1.0f / 3.0f);
    out[0] = fusion + ceq;  // question_loss_weight = 1.0
    out[1] = fusion;
    out[2] = ceq;
  }
}

// ---------------------------------------------------------------------------
extern "C" void kernel_launch(void* const* d_in, const int* in_sizes, int n_in,
                              void* d_out, int out_size, void* d_ws, size_t ws_size,
                              hipStream_t stream) {
  const float* mm_proj     = (const float*)d_in[0];
  const float* ans_emb     = (const float*)d_in[1];
  const float* v_max       = (const float*)d_in[2];
  const float* mm          = (const float*)d_in[3];
  const float* logits_q    = (const float*)d_in[4];
  const float* logits_rubi = (const float*)d_in[5];
  const int*   cid         = (const int*)d_in[6];
  float* out = (float*)d_out;

  // Workspace layout (16B-aligned):
  //   g_bf16 : 8192*512*2 = 8,388,608 B
  //   a_bf16 : 3200*512*2 = 3,276,800 B
  //   zero region: den[8192] | rowsum[16384] | acc[4]   (one memset)
  //   pos[8192], obj[8192]
  char* ws = (char*)d_ws;
  __bf16* g = (__bf16*)ws;
  __bf16* a = (__bf16*)(ws + 8388608);
  float* den    = (float*)(ws + 8388608 + 3276800);
  float* rowsum = den + B_N;
  float* acc    = rowsum + 2 * B_N;
  float* pos    = acc + 4;
  float* obj    = pos + B_N;

  hipMemsetAsync(den, 0, (size_t)(3 * B_N + 4) * sizeof(float), stream);

  prep_kernel<<<PREP_G_BLOCKS + PREP_A_BLOCKS + PREP_OBJ_BLOCKS, 256, 0,
                stream>>>(mm_proj, ans_emb, v_max, mm, g, a, obj);
  pos_kernel<<<B_N / 4, 256, 0, stream>>>(g, a, cid, pos);
  nce_gemm_kernel<<<dim3(M_PAD / 128, B_N / 128), 256, 0, stream>>>(g, a, den);
  ce_sum_kernel<<<CE_BLOCKS, 256, 0, stream>>>(logits_q, logits_rubi, rowsum);
  final_reduce_kernel<<<B_N / 256, 256, 0, stream>>>(den, pos, rowsum,
                                                     logits_q, logits_rubi,
                                                     cid, obj, acc);
  final_combine_kernel<<<1, 64, 0, stream>>>(acc, out);
}

// Round 7
// 319.354 us; speedup vs baseline: 1.0595x; 1.0325x over previous
//
#include <hip/hip_runtime.h>
#include <hip/hip_bf16.h>

#define B_N 8192
#define M_N 3129
#define M_PAD 3200
#define D_N 512

// ce streaming: each wave owns a contiguous span of 3072 floats (12 float4
// wave-loads). 3072 < 3129 => at most ONE row boundary per span => 2 buckets.
// 8192*3129 floats = 6,408,192 float4 = 100,128 wave-loads = 8344 spans/array.
#define CE_L 12
#define CE_SPAN (CE_L * 256)     // 3072 floats
#define CE_WPA 8344              // spans per array
#define CE_WTOT (2 * CE_WPA)     // 16688 total spans
// Split across the two fused launches (rebalance knob):
#define CE1_SPANS 10688
#define CE2_SPANS (CE_WTOT - CE1_SPANS)   // 6000
#define CE1_BLOCKS (CE1_SPANS / 4)        // 2672
#define CE2_BLOCKS (CE2_SPANS / 4)        // 1500

#define PREP_G_BLOCKS   (B_N / 4)      // 2048
#define PREP_A_BLOCKS   (M_PAD / 4)    // 800
#define PREP_OBJ_BLOCKS (B_N / 4)      // 2048
#define PREP_BLOCKS (PREP_G_BLOCKS + PREP_A_BLOCKS + PREP_OBJ_BLOCKS)  // 4896

#define GEMM_BLOCKS ((M_PAD / 128) * (B_N / 128))  // 25*64 = 1600
#define POS_BLOCKS  (B_N / 4)                      // 2048

#define L1_BLOCKS (CE1_BLOCKS + PREP_BLOCKS)               // 7568
#define L2_BLOCKS (GEMM_BLOCKS + CE2_BLOCKS + POS_BLOCKS)  // 5148

#define GLOBAL_AS __attribute__((address_space(1)))
#define LDS_AS __attribute__((address_space(3)))

typedef __bf16 bf16x8 __attribute__((ext_vector_type(8)));
typedef float f32x4 __attribute__((ext_vector_type(4)));

// ---------------------------------------------------------------------------
// One ce span (round-6 proven): contiguous 3072 floats, 2 row-buckets split
// by a wave-uniform bound, single end-of-wave shfl reduction, <=2 atomics.
// rowsum layout: [0..8191] = logits_q rows, [8192..16383] = logits_rubi.
__device__ __forceinline__ void ce_span(
    int gw, const float* __restrict__ lq, const float* __restrict__ lr,
    float* __restrict__ rowsum) {
  const int lane = threadIdx.x & 63;
  const int aidx = (gw >= CE_WPA) ? 1 : 0;
  const unsigned wl = (unsigned)(gw - aidx * CE_WPA);
  const unsigned f0 = wl * (unsigned)CE_SPAN;          // span start (flat)
  const unsigned r0 = f0 / (unsigned)M_N;              // magic-mul div
  const unsigned b1 = (r0 + 1u) * (unsigned)M_N;       // wave-uniform bound
  const float* base = aidx ? lr : lq;
  const float* p = base + f0 + (unsigned)lane * 4u;

  float4 buf[6];
#pragma unroll
  for (int i = 0; i < 6; ++i) buf[i] = *(const float4*)(p + i * 256);

  float a0 = 0.f, a1 = 0.f;
  const unsigned fbase = f0 + (unsigned)lane * 4u;
#pragma unroll
  for (int i = 0; i < CE_L; ++i) {
    float4 v = buf[i % 6];
    if (i + 6 < CE_L) buf[i % 6] = *(const float4*)(p + (i + 6) * 256);
    unsigned f = fbase + (unsigned)i * 256u;
    float e0 = __expf(v.x), e1 = __expf(v.y), e2 = __expf(v.z), e3 = __expf(v.w);
    float lo = 0.f, hi = 0.f;
    if (f + 0u < b1) lo += e0; else hi += e0;
    if (f + 1u < b1) lo += e1; else hi += e1;
    if (f + 2u < b1) lo += e2; else hi += e2;
    if (f + 3u < b1) lo += e3; else hi += e3;
    a0 += lo; a1 += hi;
  }
  for (int o = 1; o < 64; o <<= 1) {
    a0 += __shfl_xor(a0, o);
    a1 += __shfl_xor(a1, o);
  }
  if (lane == 0) {
    float* rs = rowsum + (aidx ? B_N : 0);
    atomicAdd(rs + r0, a0);
    if (a1 != 0.f) atomicAdd(rs + r0 + 1, a1);  // exact 0 iff no boundary
  }
}

__device__ __forceinline__ void normalize_row(
    const float* __restrict__ x, __bf16* __restrict__ y,
    int row, int nrows_src, int lane) {
  bf16x8 out;
  if (row >= nrows_src) {
    for (int j = 0; j < 8; ++j) out[j] = (__bf16)0.0f;
    *(bf16x8*)(y + (size_t)row * D_N + lane * 8) = out;
    return;
  }
  const float4* xr = (const float4*)(x + (size_t)row * D_N);
  float4 v0 = xr[lane * 2], v1 = xr[lane * 2 + 1];
  float s = v0.x*v0.x + v0.y*v0.y + v0.z*v0.z + v0.w*v0.w
          + v1.x*v1.x + v1.y*v1.y + v1.z*v1.z + v1.w*v1.w;
  for (int o = 1; o < 64; o <<= 1) s += __shfl_xor(s, o);
  float rn = 1.0f / fmaxf(sqrtf(s), 1e-8f);
  float vals[8] = {v0.x, v0.y, v0.z, v0.w, v1.x, v1.y, v1.z, v1.w};
  for (int j = 0; j < 8; ++j) out[j] = (__bf16)(vals[j] * rn);
  *(bf16x8*)(y + (size_t)row * D_N + lane * 8) = out;
}

// ---------------------------------------------------------------------------
// L1: ce1 spans + prep (normalize g/a, obj rows). ce is independent of the
// GEMM chain; overlapping it with prep raises L1 to the aggregate-BW limit
// instead of running two half-idle kernels back to back.
__global__ __launch_bounds__(256) void l1_prep_ce_kernel(
    const float* __restrict__ mm_proj, const float* __restrict__ ans_emb,
    const float* __restrict__ v_max, const float* __restrict__ mm,
    const float* __restrict__ lq, const float* __restrict__ lr,
    __bf16* __restrict__ g, __bf16* __restrict__ a,
    float* __restrict__ obj, float* __restrict__ rowsum) {
  int blk = blockIdx.x;
  int wid = threadIdx.x >> 6, lane = threadIdx.x & 63;
  if (blk < CE1_BLOCKS) {
    ce_span(blk * 4 + wid, lq, lr, rowsum);
    return;
  }
  blk -= CE1_BLOCKS;
  if (blk < PREP_G_BLOCKS) {
    normalize_row(mm_proj, g, blk * 4 + wid, B_N, lane);
  } else if (blk < PREP_G_BLOCKS + PREP_A_BLOCKS) {
    normalize_row(ans_emb, a, (blk - PREP_G_BLOCKS) * 4 + wid, M_N, lane);
  } else {
    int b = (blk - PREP_G_BLOCKS - PREP_A_BLOCKS) * 4 + wid;
    const float4* vr = (const float4*)(v_max + (size_t)b * D_N);
    const float4* mr = (const float4*)(mm + (size_t)b * D_N);
    float4 a0 = vr[lane * 2], a1 = vr[lane * 2 + 1];
    float4 b0 = mr[lane * 2], b1 = mr[lane * 2 + 1];
    float sv = a0.x*a0.x + a0.y*a0.y + a0.z*a0.z + a0.w*a0.w
             + a1.x*a1.x + a1.y*a1.y + a1.z*a1.z + a1.w*a1.w;
    float sm = b0.x*b0.x + b0.y*b0.y + b0.z*b0.z + b0.w*b0.w
             + b1.x*b1.x + b1.y*b1.y + b1.z*b1.z + b1.w*b1.w;
    float sd = a0.x*b0.x + a0.y*b0.y + a0.z*b0.z + a0.w*b0.w
             + a1.x*b1.x + a1.y*b1.y + a1.z*b1.z + a1.w*b1.w;
    for (int o = 1; o < 64; o <<= 1) {
      sv += __shfl_xor(sv, o);
      sm += __shfl_xor(sm, o);
      sd += __shfl_xor(sd, o);
    }
    if (lane == 0) {
      float dist = sd / (fmaxf(sqrtf(sv), 1e-8f) * fmaxf(sqrtf(sm), 1e-8f));
      obj[b] = 1.0f - dist;
    }
  }
}

// ---------------------------------------------------------------------------
// L2: gemm blocks first (critical path, MFMA-bound, inputs L3-warm), then
// ce2 spans (memory-bound — soaks the HBM the gemm leaves idle), then pos.
// pos recomputes the normalization from raw inputs with the EXACT op
// sequence of normalize_row (same fp32 order, no fast-math) => bit-identical
// bf16 => consistent with the MFMA d_logit to fp32 rounding.
__global__ __launch_bounds__(256) void l2_gemm_ce_pos_kernel(
    const __bf16* __restrict__ g, const __bf16* __restrict__ a,
    const int* __restrict__ cid,
    const float* __restrict__ mm_proj, const float* __restrict__ ans_emb,
    const float* __restrict__ lq, const float* __restrict__ lr,
    float* __restrict__ den, float* __restrict__ pos,
    float* __restrict__ rowsum) {
  __shared__ __bf16 As[128 * 32];
  __shared__ __bf16 Bs[128 * 32];
  int blk = blockIdx.x;
  const int t = threadIdx.x;
  const int lane = t & 63;
  const int wid = t >> 6;

  if (blk < GEMM_BLOCKS) {
    const int brow0 = (blk / (M_PAD / 128)) * 128;
    const int mrow0 = (blk % (M_PAD / 128)) * 128;
    const int wrow = wid >> 1;      // 0..1
    const int wcol = wid & 1;       // 0..1
    const int r = lane & 15;
    const int quad = lane >> 4;

    f32x4 acc[4][4];
    for (int i = 0; i < 4; ++i)
      for (int j = 0; j < 4; ++j)
        acc[i][j] = f32x4{0.f, 0.f, 0.f, 0.f};

    for (int k0 = 0; k0 < D_N; k0 += 32) {
      __syncthreads();
      for (int i = 0; i < 2; ++i) {
        int s = t + i * 256;
        int row = s >> 2;
        int kq = (s & 3) << 3;
        const __bf16* ga = g + (size_t)(brow0 + row) * D_N + (k0 + kq);
        __builtin_amdgcn_global_load_lds((const GLOBAL_AS void*)ga,
                                         (LDS_AS void*)(As + s * 8), 16, 0, 0);
        const __bf16* gb = a + (size_t)(mrow0 + row) * D_N + (k0 + kq);
        __builtin_amdgcn_global_load_lds((const GLOBAL_AS void*)gb,
                                         (LDS_AS void*)(Bs + s * 8), 16, 0, 0);
      }
      __syncthreads();
      bf16x8 af[4], bf[4];
      for (int i = 0; i < 4; ++i)
        af[i] = *(const bf16x8*)(As + (wrow * 64 + i * 16 + r) * 32 + quad * 8);
      for (int j = 0; j < 4; ++j)
        bf[j] = *(const bf16x8*)(Bs + (wcol * 64 + j * 16 + r) * 32 + quad * 8);
      for (int i = 0; i < 4; ++i)
        for (int j = 0; j < 4; ++j)
          acc[i][j] = __builtin_amdgcn_mfma_f32_16x16x32_bf16(af[i], bf[j],
                                                              acc[i][j], 0, 0, 0);
    }

    // C/D layout: col = lane&15, row = quad*4 + reg.
    for (int i = 0; i < 4; ++i) {
      for (int reg = 0; reg < 4; ++reg) {
        float s = 0.0f;
        for (int j = 0; j < 4; ++j) {
          int m = mrow0 + wcol * 64 + j * 16 + r;
          if (m < M_N) s += __expf(acc[i][j][reg]);
        }
        s += __shfl_xor(s, 1);
        s += __shfl_xor(s, 2);
        s += __shfl_xor(s, 4);
        s += __shfl_xor(s, 8);
        if (r == 0) {
          int b = brow0 + wrow * 64 + i * 16 + quad * 4 + reg;
          atomicAdd(den + b, s);
        }
      }
    }
    return;
  }
  blk -= GEMM_BLOCKS;

  if (blk < CE2_BLOCKS) {
    ce_span(CE1_SPANS + blk * 4 + wid, lq, lr, rowsum);
    return;
  }
  blk -= CE2_BLOCKS;

  // pos role: b = blk*4 + wid. Recompute both normalized bf16 rows locally.
  {
    int b = blk * 4 + wid;
    int label = cid[b];
    const float4* xr = (const float4*)(mm_proj + (size_t)b * D_N);
    float4 v0 = xr[lane * 2], v1 = xr[lane * 2 + 1];
    const float4* yr = (const float4*)(ans_emb + (size_t)label * D_N);
    float4 w0 = yr[lane * 2], w1 = yr[lane * 2 + 1];
    float sg = v0.x*v0.x + v0.y*v0.y + v0.z*v0.z + v0.w*v0.w
             + v1.x*v1.x + v1.y*v1.y + v1.z*v1.z + v1.w*v1.w;
    float sa = w0.x*w0.x + w0.y*w0.y + w0.z*w0.z + w0.w*w0.w
             + w1.x*w1.x + w1.y*w1.y + w1.z*w1.z + w1.w*w1.w;
    for (int o = 1; o < 64; o <<= 1) {
      sg += __shfl_xor(sg, o);
      sa += __shfl_xor(sa, o);
    }
    float rng = 1.0f / fmaxf(sqrtf(sg), 1e-8f);
    float rna = 1.0f / fmaxf(sqrtf(sa), 1e-8f);
    float gv[8] = {v0.x, v0.y, v0.z, v0.w, v1.x, v1.y, v1.z, v1.w};
    float av[8] = {w0.x, w0.y, w0.z, w0.w, w1.x, w1.y, w1.z, w1.w};
    float d = 0.0f;
    for (int j = 0; j < 8; ++j)
      d += (float)(__bf16)(gv[j] * rng) * (float)(__bf16)(av[j] * rna);
    for (int o = 1; o < 64; o <<= 1) d += __shfl_xor(d, o);
    if (lane == 0) pos[b] = d;
  }
}

// ---------------------------------------------------------------------------
// Final reduce: per-row losses -> acc[0..3] (32 adders/address). Folds the
// CE finish (log(rowsum) - label gather) in. acc must be pre-zeroed.
__global__ __launch_bounds__(256) void final_reduce_kernel(
    const float* __restrict__ den, const float* __restrict__ pos,
    const float* __restrict__ rowsum,
    const float* __restrict__ lq, const float* __restrict__ lr,
    const int* __restrict__ cid, const float* __restrict__ obj,
    float* __restrict__ acc) {
  int b = blockIdx.x * 256 + threadIdx.x;  // 32*256 == B_N exactly
  int lab = cid[b];
  float xq = lq[(size_t)b * M_N + lab];
  float xr = lr[(size_t)b * M_N + lab];
  float s_nce = logf(den[b]) - pos[b];
  float s_ceq = logf(rowsum[b]) - xq;
  float s_cer = logf(rowsum[B_N + b]) - xr;
  float s_obj = obj[b];
  for (int o = 1; o < 64; o <<= 1) {
    s_nce += __shfl_xor(s_nce, o);
    s_ceq += __shfl_xor(s_ceq, o);
    s_cer += __shfl_xor(s_cer, o);
    s_obj += __shfl_xor(s_obj, o);
  }
  __shared__ float red[4][4];
  int wid = threadIdx.x >> 6;
  if ((threadIdx.x & 63) == 0) {
    red[wid][0] = s_nce; red[wid][1] = s_ceq;
    red[wid][2] = s_cer; red[wid][3] = s_obj;
  }
  __syncthreads();
  if (threadIdx.x < 4) {
    float v = red[0][threadIdx.x] + red[1][threadIdx.x]
            + red[2][threadIdx.x] + red[3][threadIdx.x];
    atomicAdd(acc + threadIdx.x, v);
  }
}

// Stage 2: combine.
__global__ void final_combine_kernel(const float* __restrict__ acc,
                                     float* __restrict__ out) {
  if (threadIdx.x == 0) {
    float nce = acc[0] / (float)B_N;
    float ceq = acc[1] / (float)B_N;
    float cer = acc[2] / (float)B_N;
    float ob  = acc[3] / (float)B_N;
    float fusion = (cer + ob + nce) * (1.0f / 3.0f);
    out[0] = fusion + ceq;  // question_loss_weight = 1.0
    out[1] = fusion;
    out[2] = ceq;
  }
}

// ---------------------------------------------------------------------------
extern "C" void kernel_launch(void* const* d_in, const int* in_sizes, int n_in,
                              void* d_out, int out_size, void* d_ws, size_t ws_size,
                              hipStream_t stream) {
  const float* mm_proj     = (const float*)d_in[0];
  const float* ans_emb     = (const float*)d_in[1];
  const float* v_max       = (const float*)d_in[2];
  const float* mm          = (const float*)d_in[3];
  const float* logits_q    = (const float*)d_in[4];
  const float* logits_rubi = (const float*)d_in[5];
  const int*   cid         = (const int*)d_in[6];
  float* out = (float*)d_out;

  // Workspace layout (16B-aligned):
  //   g_bf16 : 8192*512*2 = 8,388,608 B
  //   a_bf16 : 3200*512*2 = 3,276,800 B
  //   zero region: den[8192] | rowsum[16384] | acc[4]   (one memset)
  //   pos[8192], obj[8192]
  char* ws = (char*)d_ws;
  __bf16* g = (__bf16*)ws;
  __bf16* a = (__bf16*)(ws + 8388608);
  float* den    = (float*)(ws + 8388608 + 3276800);
  float* rowsum = den + B_N;
  float* acc    = rowsum + 2 * B_N;
  float* pos    = acc + 4;
  float* obj    = pos + B_N;

  hipMemsetAsync(den, 0, (size_t)(3 * B_N + 4) * sizeof(float), stream);

  l1_prep_ce_kernel<<<L1_BLOCKS, 256, 0, stream>>>(
      mm_proj, ans_emb, v_max, mm, logits_q, logits_rubi, g, a, obj, rowsum);
  l2_gemm_ce_pos_kernel<<<L2_BLOCKS, 256, 0, stream>>>(
      g, a, cid, mm_proj, ans_emb, logits_q, logits_rubi, den, pos, rowsum);
  final_reduce_kernel<<<B_N / 256, 256, 0, stream>>>(den, pos, rowsum,
                                                     logits_q, logits_rubi,
                                                     cid, obj, acc);
  final_combine_kernel<<<1, 64, 0, stream>>>(acc, out);
}